// Round 10
// baseline (10657.069 us; speedup 1.0000x reference)
//
#include <hip/hip_runtime.h>

#define NN   2048
#define NBLK 256
#define TPB  512
#define CPB  8          // columns per block (one 64-lane wave per column)
#define SENT 1.0e30f    // finite "infinity" sentinel (fast-math-proof)

typedef unsigned long long u64;

struct BFWS {
  u64 pub[2][NN];    // (tag<<32)|fp32bits, double-buffered by round parity
  u64 cyc[NBLK];     // (tag NN<<32)|viol  for the negative-cycle gather
};

// Relaxed agent-scope atomics: serviced at the device coherence point (MALL);
// no acquire/release cache invalidates. 8-byte store is single-copy atomic,
// so tag+value publish in ONE hop.
__device__ __forceinline__ u64 ld64(u64* p) {
  return __hip_atomic_load(p, __ATOMIC_RELAXED, __HIP_MEMORY_SCOPE_AGENT);
}
__device__ __forceinline__ void st64(u64* p, u64 v) {
  __hip_atomic_store(p, v, __ATOMIC_RELAXED, __HIP_MEMORY_SCOPE_AGENT);
}

__global__ void bf_init(BFWS* ws) {
  int t = threadIdx.x;
  if (t < NBLK) ws->cyc[t] = 0ull;   // tag 0: never matches (rounds are >=1)
}

__global__ void __launch_bounds__(TPB, 1)
bf_main(const float* __restrict__ A, const int* __restrict__ srcp,
        float* __restrict__ dist, float* __restrict__ pred,
        float* __restrict__ flagout, BFWS* ws) {
  const int tid = threadIdx.x;
  const int b   = blockIdx.x;
  const int c   = tid >> 6;       // column within block (0..7), one wave each
  const int s   = tid & 63;       // lane within wave
  const int col = b * CPB + c;
  const int src = srcp[0];

  __shared__ __align__(16) float d_lds[2][NN];   // double-buffered d vector
  __shared__ int bflag;

  // ---- adjacency slice into registers: a[4k+m] = A[i][col], i = 4(s+64k)+m ----
  float a[32];
  #pragma unroll
  for (int k = 0; k < 8; ++k) {
    #pragma unroll
    for (int m = 0; m < 4; ++m) {
      int i = 4 * (s + 64 * k) + m;
      a[4 * k + m] = A[(size_t)i * NN + col];
    }
  }

  // ---- d0 into LDS buffer 0 (round 1 reads buf[0]) ----
  #pragma unroll
  for (int h = 0; h < 4; ++h) {
    int e = h * TPB + tid;
    d_lds[0][e] = (e == src) ? 0.f : SENT;
  }
  if (s == 0) {
    dist[(size_t)col * NN] = (col == src) ? 0.f : SENT;
    pred[(size_t)col * NN] = 0.f;
  }
  __syncthreads();

  for (int t = 1; t <= NN - 1; ++t) {
    if (t > 1) {
      // ---- branchless busy-poll of round t-1: 4 tagged words per thread ----
      u64* pb = ws->pub[(t - 1) & 1];
      const unsigned want = (unsigned)(t - 1);
      u64 v0, v1, v2, v3;
      for (;;) {
        v0 = ld64(pb + 0 * TPB + tid);
        v1 = ld64(pb + 1 * TPB + tid);
        v2 = ld64(pb + 2 * TPB + tid);
        v3 = ld64(pb + 3 * TPB + tid);
        bool ok = ((unsigned)(v0 >> 32) == want) &
                  ((unsigned)(v1 >> 32) == want) &
                  ((unsigned)(v2 >> 32) == want) &
                  ((unsigned)(v3 >> 32) == want);
        if (ok) break;
      }
      float* dst = d_lds[(t - 1) & 1];
      dst[0 * TPB + tid] = __uint_as_float((unsigned)v0);
      dst[1 * TPB + tid] = __uint_as_float((unsigned)v1);
      dst[2 * TPB + tid] = __uint_as_float((unsigned)v2);
      dst[3 * TPB + tid] = __uint_as_float((unsigned)v3);
      __syncthreads();   // single barrier per round (buffer-safety by parity)
    }

    // ---- min-plus over this thread's 32 i's, 4 independent chains ----
    float bv0 = 2.f * SENT, bv1 = 2.f * SENT, bv2 = 2.f * SENT, bv3 = 2.f * SENT;
    int   bi0 = 0,          bi1 = 1,          bi2 = 2,          bi3 = 3;
    const float4* dq4 = reinterpret_cast<const float4*>(d_lds[(t - 1) & 1]);
    #pragma unroll
    for (int k = 0; k < 8; ++k) {
      float4 dq = dq4[s + 64 * k];
      int base = 4 * (s + 64 * k);
      float c0 = dq.x + a[4 * k + 0];
      float c1 = dq.y + a[4 * k + 1];
      float c2 = dq.z + a[4 * k + 2];
      float c3 = dq.w + a[4 * k + 3];
      if (c0 < bv0) { bv0 = c0; bi0 = base + 0; }
      if (c1 < bv1) { bv1 = c1; bi1 = base + 1; }
      if (c2 < bv2) { bv2 = c2; bi2 = base + 2; }
      if (c3 < bv3) { bv3 = c3; bi3 = base + 3; }
    }
    // merge chains with (value, smaller-index) lexicographic rule
    float bv = bv0; int bi = bi0;
    if (bv1 < bv || (bv1 == bv && bi1 < bi)) { bv = bv1; bi = bi1; }
    if (bv2 < bv || (bv2 == bv && bi2 < bi)) { bv = bv2; bi = bi2; }
    if (bv3 < bv || (bv3 == bv && bi3 < bi)) { bv = bv3; bi = bi3; }
    // butterfly across the 64 lanes of this column's wave
    #pragma unroll
    for (int off = 32; off; off >>= 1) {
      float ov = __shfl_xor(bv, off, 64);
      int   oi = __shfl_xor(bi, off, 64);
      if (ov < bv || (ov == bv && oi < bi)) { bv = ov; bi = oi; }
    }

    // publish FIRST (critical path): one 8B atomic = tag + value
    if (s == 0)
      st64(&ws->pub[t & 1][col], ((u64)(unsigned)t << 32) | (u64)__float_as_uint(bv));
    if (s == 1) {                     // outputs off the publisher lane
      dist[(size_t)col * NN + t] = bv;
      pred[(size_t)col * NN + t] = (float)bi;
    }
  }

  // ---- negative-cycle check on P_{NN-1} (slot (NN-1)&1 = 1) ----
  {
    u64* pb = ws->pub[(NN - 1) & 1];
    const unsigned want = (unsigned)(NN - 1);
    u64 v0, v1, v2, v3;
    for (;;) {
      v0 = ld64(pb + 0 * TPB + tid);
      v1 = ld64(pb + 1 * TPB + tid);
      v2 = ld64(pb + 2 * TPB + tid);
      v3 = ld64(pb + 3 * TPB + tid);
      bool ok = ((unsigned)(v0 >> 32) == want) &
                ((unsigned)(v1 >> 32) == want) &
                ((unsigned)(v2 >> 32) == want) &
                ((unsigned)(v3 >> 32) == want);
      if (ok) break;
    }
    d_lds[1][0 * TPB + tid] = __uint_as_float((unsigned)v0);
    d_lds[1][1 * TPB + tid] = __uint_as_float((unsigned)v1);
    d_lds[1][2 * TPB + tid] = __uint_as_float((unsigned)v2);
    d_lds[1][3 * TPB + tid] = __uint_as_float((unsigned)v3);
    if (tid == 0) bflag = 0;
    __syncthreads();

    float dj = d_lds[1][col];
    int viol = 0;
    const float4* dq4 = reinterpret_cast<const float4*>(d_lds[1]);
    #pragma unroll
    for (int k = 0; k < 8; ++k) {
      float4 dq = dq4[s + 64 * k];
      viol |= (dq.x + a[4 * k + 0] < dj);
      viol |= (dq.y + a[4 * k + 1] < dj);
      viol |= (dq.z + a[4 * k + 2] < dj);
      viol |= (dq.w + a[4 * k + 3] < dj);
    }
    if (viol) bflag = 1;      // benign same-value race within block
    __syncthreads();
    if (tid == 0)
      st64(&ws->cyc[b], ((u64)(unsigned)NN << 32) | (u64)(unsigned)bflag);
  }

  // ---- block 0 gathers the 256 tagged viol bits and writes the flag ----
  if (b == 0) {
    int myv = 0;
    if (tid < NBLK) {
      u64 w;
      do { w = ld64(&ws->cyc[tid]); } while ((unsigned)(w >> 32) != (unsigned)NN);
      myv = (int)((unsigned)w & 1u);
    }
    if (tid == 0) bflag = 0;
    __syncthreads();
    if (myv) bflag = 1;       // benign same-value race
    __syncthreads();
    if (tid == 0) flagout[0] = bflag ? 1.f : 0.f;
  }
}

extern "C" void kernel_launch(void* const* d_in, const int* in_sizes, int n_in,
                              void* d_out, int out_size, void* d_ws, size_t ws_size,
                              hipStream_t stream) {
  (void)in_sizes; (void)n_in; (void)out_size; (void)ws_size;
  const float* A    = (const float*)d_in[0];
  const int*   srcp = (const int*)d_in[1];
  float* dist    = (float*)d_out;
  float* pred    = dist + (size_t)NN * NN;
  float* flagout = dist + (size_t)2 * NN * NN;
  BFWS*  ws      = (BFWS*)d_ws;

  bf_init<<<1, 256, 0, stream>>>(ws);
  bf_main<<<dim3(NBLK), dim3(TPB), 0, stream>>>(A, srcp, dist, pred, flagout, ws);
}

// Round 11
// 7825.493 us; speedup vs baseline: 1.3618x; 1.3618x over previous
//
#include <hip/hip_runtime.h>

#define NN   2048
#define NBLK 256
#define TPB  256
#define CPB  8          // columns per block
#define SENT 1.0e30f    // finite "infinity" sentinel (fast-math-proof)

typedef unsigned long long u64;

struct BFWS {
  u64 pub[2][NN];    // (tag<<32)|fp32bits, double-buffered by round parity
  u64 cyc[NBLK];     // (tag NN<<32)|viol  for the negative-cycle gather
};

__device__ __forceinline__ u64 ld64(u64* p) {
  return __hip_atomic_load(p, __ATOMIC_RELAXED, __HIP_MEMORY_SCOPE_AGENT);
}
// Non-posted publish: atomic swap issues straight to the coherence point
// (no write-combine lingering), result discarded.
__device__ __forceinline__ void stx(u64* p, u64 v) {
  (void)__hip_atomic_exchange(p, v, __ATOMIC_RELAXED, __HIP_MEMORY_SCOPE_AGENT);
}

__global__ void bf_init(BFWS* ws) {
  int t = threadIdx.x;
  if (t < NBLK) ws->cyc[t] = 0ull;   // tag 0: never matches (rounds are >=1)
}

__global__ void __launch_bounds__(TPB, 1)
bf_main(const float* __restrict__ A, const int* __restrict__ srcp,
        float* __restrict__ dist, float* __restrict__ pred,
        float* __restrict__ flagout, BFWS* ws) {
  const int tid = threadIdx.x;
  const int b   = blockIdx.x;
  const int c   = tid >> 5;       // column within block (0..7)
  const int s   = tid & 31;       // i-slice (0..31)
  const int col = b * CPB + c;
  const int src = srcp[0];

  __shared__ __align__(16) float d_lds[2][NN];   // double-buffered d vector
  __shared__ int bflag;
  __shared__ int wv[4];

  // ---- adjacency slice into registers: a[4k+m] = A[i][col], i = 4s+128k+m ----
  float a[64];
  #pragma unroll
  for (int k = 0; k < 16; ++k) {
    #pragma unroll
    for (int m = 0; m < 4; ++m) {
      int i = 4 * s + 128 * k + m;
      a[4 * k + m] = A[(size_t)i * NN + col];
    }
  }

  // ---- d0 into LDS buffer 0 (round 1 reads buf[(1-1)&1] = buf[0]) ----
  #pragma unroll
  for (int h = 0; h < 8; ++h) {
    int e = h * TPB + tid;
    d_lds[0][e] = (e == src) ? 0.f : SENT;
  }
  if (s == 0) {
    dist[(size_t)col * NN] = (col == src) ? 0.f : SENT;
    pred[(size_t)col * NN] = 0.f;
  }
  __syncthreads();

  for (int t = 1; t <= NN - 1; ++t) {
    if (t > 1) {
      // ---- poll+stage round t-1: each thread owns 8 tagged words ----
      u64* pb = ws->pub[(t - 1) & 1];
      const unsigned want = (unsigned)(t - 1);
      u64 v[8];
      unsigned got = 0;
      while (got != 0xFFu) {
        #pragma unroll
        for (int h = 0; h < 8; ++h)
          if (!((got >> h) & 1)) v[h] = ld64(pb + h * TPB + tid);
        #pragma unroll
        for (int h = 0; h < 8; ++h)
          if (!((got >> h) & 1) && (unsigned)(v[h] >> 32) == want) got |= 1u << h;
        if (got != 0xFFu) __builtin_amdgcn_s_sleep(1);
      }
      #pragma unroll
      for (int h = 0; h < 8; ++h)
        d_lds[(t - 1) & 1][h * TPB + tid] = __uint_as_float((unsigned)v[h]);
      __syncthreads();   // single barrier per round (buffer-safety by parity)
    }

    // ---- min-plus over this thread's 64 i's, 4 independent chains ----
    float bv0 = SENT * 2.f, bv1 = SENT * 2.f, bv2 = SENT * 2.f, bv3 = SENT * 2.f;
    int   bi0 = 0,          bi1 = 1,          bi2 = 2,          bi3 = 3;
    const float4* dq4 = reinterpret_cast<const float4*>(d_lds[(t - 1) & 1]);
    #pragma unroll
    for (int k = 0; k < 16; ++k) {
      float4 dq = dq4[s + 32 * k];
      int base = 4 * s + 128 * k;
      float c0 = dq.x + a[4 * k + 0];
      float c1 = dq.y + a[4 * k + 1];
      float c2 = dq.z + a[4 * k + 2];
      float c3 = dq.w + a[4 * k + 3];
      if (c0 < bv0) { bv0 = c0; bi0 = base + 0; }
      if (c1 < bv1) { bv1 = c1; bi1 = base + 1; }
      if (c2 < bv2) { bv2 = c2; bi2 = base + 2; }
      if (c3 < bv3) { bv3 = c3; bi3 = base + 3; }
    }
    // merge chains with first-index tie-break
    float bv = bv0; int bi = bi0;
    if (bv1 < bv || (bv1 == bv && bi1 < bi)) { bv = bv1; bi = bi1; }
    if (bv2 < bv || (bv2 == bv && bi2 < bi)) { bv = bv2; bi = bi2; }
    if (bv3 < bv || (bv3 == bv && bi3 < bi)) { bv = bv3; bi = bi3; }
    // butterfly across the 32 lanes of this column group
    #pragma unroll
    for (int off = 16; off; off >>= 1) {
      float ov = __shfl_xor(bv, off, 32);
      int   oi = __shfl_xor(bi, off, 32);
      if (ov < bv || (ov == bv && oi < bi)) { bv = ov; bi = oi; }
    }

    // publish FIRST (critical path): one 8B non-posted atomic = tag + value
    if (s == 0)
      stx(&ws->pub[t & 1][col], ((u64)(unsigned)t << 32) | (u64)__float_as_uint(bv));
    if (s == 1) {                     // outputs off the publisher lane
      dist[(size_t)col * NN + t] = bv;
      pred[(size_t)col * NN + t] = (float)bi;
    }
  }

  // ---- negative-cycle check on P_{NN-1} (slot (NN-1)&1 = 1) ----
  {
    u64* pb = ws->pub[(NN - 1) & 1];
    const unsigned want = (unsigned)(NN - 1);
    u64 v[8];
    unsigned got = 0;
    while (got != 0xFFu) {
      #pragma unroll
      for (int h = 0; h < 8; ++h)
        if (!((got >> h) & 1)) v[h] = ld64(pb + h * TPB + tid);
      #pragma unroll
      for (int h = 0; h < 8; ++h)
        if (!((got >> h) & 1) && (unsigned)(v[h] >> 32) == want) got |= 1u << h;
      if (got != 0xFFu) __builtin_amdgcn_s_sleep(1);
    }
    #pragma unroll
    for (int h = 0; h < 8; ++h)
      d_lds[1][h * TPB + tid] = __uint_as_float((unsigned)v[h]);
    if (tid == 0) bflag = 0;
    __syncthreads();

    float dj = d_lds[1][col];
    int viol = 0;
    const float4* dq4 = reinterpret_cast<const float4*>(d_lds[1]);
    #pragma unroll
    for (int k = 0; k < 16; ++k) {
      float4 dq = dq4[s + 32 * k];
      viol |= (dq.x + a[4 * k + 0] < dj);
      viol |= (dq.y + a[4 * k + 1] < dj);
      viol |= (dq.z + a[4 * k + 2] < dj);
      viol |= (dq.w + a[4 * k + 3] < dj);
    }
    if (viol) bflag = 1;      // benign same-value race within block
    __syncthreads();
    if (tid == 0)
      stx(&ws->cyc[b], ((u64)(unsigned)NN << 32) | (u64)(unsigned)bflag);
  }

  // ---- block 0 gathers the 256 tagged viol bits and writes the flag ----
  if (b == 0) {
    u64 w;
    do {
      w = ld64(&ws->cyc[tid]);
      if ((unsigned)(w >> 32) == (unsigned)NN) break;
      __builtin_amdgcn_s_sleep(1);
    } while (true);
    int myv = (int)((unsigned)w & 1u);
    int anyv = __any(myv);
    if ((tid & 63) == 0) wv[tid >> 6] = anyv;
    __syncthreads();
    if (tid == 0)
      flagout[0] = (wv[0] | wv[1] | wv[2] | wv[3]) ? 1.f : 0.f;
  }
}

extern "C" void kernel_launch(void* const* d_in, const int* in_sizes, int n_in,
                              void* d_out, int out_size, void* d_ws, size_t ws_size,
                              hipStream_t stream) {
  (void)in_sizes; (void)n_in; (void)out_size; (void)ws_size;
  const float* A    = (const float*)d_in[0];
  const int*   srcp = (const int*)d_in[1];
  float* dist    = (float*)d_out;
  float* pred    = dist + (size_t)NN * NN;
  float* flagout = dist + (size_t)2 * NN * NN;
  BFWS*  ws      = (BFWS*)d_ws;

  bf_init<<<1, 256, 0, stream>>>(ws);
  bf_main<<<dim3(NBLK), dim3(TPB), 0, stream>>>(A, srcp, dist, pred, flagout, ws);
}

// Round 12
// 4139.568 us; speedup vs baseline: 2.5744x; 1.8904x over previous
//
#include <hip/hip_runtime.h>

#define NN   2048
#define NBLK 256
#define TPB  512
#define CPB  8          // columns per block, one 64-lane wave per column
#define SENT 1.0e30f    // finite "infinity" sentinel (fast-math-proof)

typedef unsigned long long u64;

struct BFWS {
  u64 pub[2][NN];    // (tag<<32)|fp32bits, double-buffered by round parity
  u64 cyc[NBLK];     // (tag NN<<32)|viol  for the negative-cycle gather
};

__device__ __forceinline__ u64 ld64(u64* p) {
  return __hip_atomic_load(p, __ATOMIC_RELAXED, __HIP_MEMORY_SCOPE_AGENT);
}
__device__ __forceinline__ void st64(u64* p, u64 v) {
  __hip_atomic_store(p, v, __ATOMIC_RELAXED, __HIP_MEMORY_SCOPE_AGENT);
}

__global__ void bf_init(BFWS* ws) {
  int t = threadIdx.x;
  if (t < NBLK) ws->cyc[t] = 0ull;   // tag 0: never matches (rounds are >=1)
}

__global__ void __launch_bounds__(TPB, 1)
bf_main(const float* __restrict__ A, const int* __restrict__ srcp,
        float* __restrict__ dist, float* __restrict__ pred,
        float* __restrict__ flagout, BFWS* ws) {
  const int tid = threadIdx.x;
  const int b   = blockIdx.x;
  const int c   = tid >> 6;       // column within block (0..7), one wave each
  const int s   = tid & 63;       // lane within the column's wave
  const int col = b * CPB + c;
  const int src = srcp[0];

  __shared__ __align__(16) float d_lds[2][NN];   // double-buffered d vector
  __shared__ int bflag;

  // ---- adjacency slice into registers: a[4k+m] = A[i][col], i = 4(s+64k)+m ----
  float a[32];
  #pragma unroll
  for (int k = 0; k < 8; ++k) {
    #pragma unroll
    for (int m = 0; m < 4; ++m) {
      int i = 4 * (s + 64 * k) + m;
      a[4 * k + m] = A[(size_t)i * NN + col];
    }
  }

  // ---- d0 into LDS buffer 0 (round 1 reads buf[0]) ----
  #pragma unroll
  for (int h = 0; h < 4; ++h) {
    int e = h * TPB + tid;
    d_lds[0][e] = (e == src) ? 0.f : SENT;
  }
  if (s == 0) {
    dist[(size_t)col * NN] = (col == src) ? 0.f : SENT;
    pred[(size_t)col * NN] = 0.f;
  }
  __syncthreads();

  for (int t = 1; t <= NN - 1; ++t) {
    if (t > 1) {
      // ---- poll+stage round t-1: 4 tagged words/thread, got-mask + backoff ----
      u64* pb = ws->pub[(t - 1) & 1];
      const unsigned want = (unsigned)(t - 1);
      u64 v[4];
      unsigned got = 0;
      while (got != 0xFu) {
        #pragma unroll
        for (int h = 0; h < 4; ++h)
          if (!((got >> h) & 1)) v[h] = ld64(pb + h * TPB + tid);
        #pragma unroll
        for (int h = 0; h < 4; ++h)
          if (!((got >> h) & 1) && (unsigned)(v[h] >> 32) == want) got |= 1u << h;
        if (got != 0xFu) __builtin_amdgcn_s_sleep(1);
      }
      // each tagged word carries ONE fp32 (low half); store 4 floats
      float* dst = d_lds[(t - 1) & 1];
      #pragma unroll
      for (int h = 0; h < 4; ++h)
        dst[h * TPB + tid] = __uint_as_float((unsigned)v[h]);
      __syncthreads();   // single barrier per round (buffer-safety by parity)
    }

    // ---- min-plus over this thread's 32 i's, 4 independent chains ----
    float bv0 = 2.f * SENT, bv1 = 2.f * SENT, bv2 = 2.f * SENT, bv3 = 2.f * SENT;
    int   bi0 = 0,          bi1 = 1,          bi2 = 2,          bi3 = 3;
    const float4* dq4 = reinterpret_cast<const float4*>(d_lds[(t - 1) & 1]);
    #pragma unroll
    for (int k = 0; k < 8; ++k) {
      float4 dq = dq4[s + 64 * k];
      int base = 4 * (s + 64 * k);
      float c0 = dq.x + a[4 * k + 0];
      float c1 = dq.y + a[4 * k + 1];
      float c2 = dq.z + a[4 * k + 2];
      float c3 = dq.w + a[4 * k + 3];
      if (c0 < bv0) { bv0 = c0; bi0 = base + 0; }
      if (c1 < bv1) { bv1 = c1; bi1 = base + 1; }
      if (c2 < bv2) { bv2 = c2; bi2 = base + 2; }
      if (c3 < bv3) { bv3 = c3; bi3 = base + 3; }
    }

    // ---- FAST PATH: value-only reduce -> publish ASAP ----
    float mv = fminf(fminf(bv0, bv1), fminf(bv2, bv3));
    #pragma unroll
    for (int off = 32; off; off >>= 1)
      mv = fminf(mv, __shfl_xor(mv, off, 64));
    if (s == 0)
      st64(&ws->pub[t & 1][col], ((u64)(unsigned)t << 32) | (u64)__float_as_uint(mv));

    // ---- SLOW PATH (off critical path): argmin with first-index tie-break ----
    float bv = bv0; int bi = bi0;
    if (bv1 < bv || (bv1 == bv && bi1 < bi)) { bv = bv1; bi = bi1; }
    if (bv2 < bv || (bv2 == bv && bi2 < bi)) { bv = bv2; bi = bi2; }
    if (bv3 < bv || (bv3 == bv && bi3 < bi)) { bv = bv3; bi = bi3; }
    #pragma unroll
    for (int off = 32; off; off >>= 1) {
      float ov = __shfl_xor(bv, off, 64);
      int   oi = __shfl_xor(bi, off, 64);
      if (ov < bv || (ov == bv && oi < bi)) { bv = ov; bi = oi; }
    }
    if (s == 1) {
      dist[(size_t)col * NN + t] = bv;
      pred[(size_t)col * NN + t] = (float)bi;
    }
  }

  // ---- negative-cycle check on P_{NN-1} (slot (NN-1)&1 = 1) ----
  {
    u64* pb = ws->pub[(NN - 1) & 1];
    const unsigned want = (unsigned)(NN - 1);
    u64 v[4];
    unsigned got = 0;
    while (got != 0xFu) {
      #pragma unroll
      for (int h = 0; h < 4; ++h)
        if (!((got >> h) & 1)) v[h] = ld64(pb + h * TPB + tid);
      #pragma unroll
      for (int h = 0; h < 4; ++h)
        if (!((got >> h) & 1) && (unsigned)(v[h] >> 32) == want) got |= 1u << h;
      if (got != 0xFu) __builtin_amdgcn_s_sleep(1);
    }
    #pragma unroll
    for (int h = 0; h < 4; ++h)
      d_lds[1][h * TPB + tid] = __uint_as_float((unsigned)v[h]);
    if (tid == 0) bflag = 0;
    __syncthreads();

    float dj = d_lds[1][col];
    int viol = 0;
    const float4* dq4 = reinterpret_cast<const float4*>(d_lds[1]);
    #pragma unroll
    for (int k = 0; k < 8; ++k) {
      float4 dq = dq4[s + 64 * k];
      viol |= (dq.x + a[4 * k + 0] < dj);
      viol |= (dq.y + a[4 * k + 1] < dj);
      viol |= (dq.z + a[4 * k + 2] < dj);
      viol |= (dq.w + a[4 * k + 3] < dj);
    }
    if (viol) bflag = 1;      // benign same-value race within block
    __syncthreads();
    if (tid == 0)
      st64(&ws->cyc[b], ((u64)(unsigned)NN << 32) | (u64)(unsigned)bflag);
  }

  // ---- block 0 gathers the 256 tagged viol bits and writes the flag ----
  if (b == 0) {
    int myv = 0;
    if (tid < NBLK) {
      u64 w;
      do {
        w = ld64(&ws->cyc[tid]);
        if ((unsigned)(w >> 32) == (unsigned)NN) break;
        __builtin_amdgcn_s_sleep(1);
      } while (true);
      myv = (int)((unsigned)w & 1u);
    }
    if (tid == 0) bflag = 0;
    __syncthreads();
    if (myv) bflag = 1;       // benign same-value race
    __syncthreads();
    if (tid == 0) flagout[0] = bflag ? 1.f : 0.f;
  }
}

extern "C" void kernel_launch(void* const* d_in, const int* in_sizes, int n_in,
                              void* d_out, int out_size, void* d_ws, size_t ws_size,
                              hipStream_t stream) {
  (void)in_sizes; (void)n_in; (void)out_size; (void)ws_size;
  const float* A    = (const float*)d_in[0];
  const int*   srcp = (const int*)d_in[1];
  float* dist    = (float*)d_out;
  float* pred    = dist + (size_t)NN * NN;
  float* flagout = dist + (size_t)2 * NN * NN;
  BFWS*  ws      = (BFWS*)d_ws;

  bf_init<<<1, 256, 0, stream>>>(ws);
  bf_main<<<dim3(NBLK), dim3(TPB), 0, stream>>>(A, srcp, dist, pred, flagout, ws);
}